// Round 1
// baseline (2368.690 us; speedup 1.0000x reference)
//
#include <hip/hip_runtime.h>
#include <math.h>

#ifndef M_PI
#define M_PI 3.14159265358979323846
#endif

// ---------------- constants ----------------
#define NSIDE 128
#define NVOX  2097152          // 128^3
#define KBINS 100
#define NFIELDS 16             // 8 pred + 8 target
#define NORMF (27.0f / 2097152.0f)   // LPIX^3 / N^3

// ws layout (bytes)
#define WS_SUMS_OFF   0                       // float[16*101]
#define WS_CNT_OFF    6464                    // int[101]
#define WS_IDS_OFF    8192                    // uint8[NVOX]
#define WS_CPLX_OFF   (8192 + 2097152)        // float2[NVOX]

// ---------------- exact numpy binning replication (fp64) ----------------
__device__ __forceinline__ double bin_edge(int i, double start, double step, double stop) {
    if (i == 100) return stop;                       // linspace sets last edge exactly
    return __dadd_rn(__dmul_rn((double)i, step), start);  // i*step + start, no FMA
}

__device__ __forceinline__ void bin_params(double* start, double* step, double* stop) {
    const double inv   = 1.0 / 384.0;                // 1/(n*d)
    const double twopi = 2.0 * M_PI;
    // start = kmag at (0,0,1) computed with numpy's op order
    double k1 = __dmul_rn(twopi, __dmul_rn(1.0, inv));
    *start = sqrt(__dadd_rn(__dadd_rn(0.0, 0.0), __dmul_rn(k1, k1)));
    // stop = kmag at (64,64,64): f = -64
    double k64 = __dmul_rn(twopi, __dmul_rn(-64.0, inv));
    double s64 = __dmul_rn(k64, k64);
    *stop = sqrt(__dadd_rn(__dadd_rn(s64, s64), s64));
    *step = (*stop - *start) / 100.0;
}

__device__ int compute_bin(int ix, int iy, int iz) {
    const double inv   = 1.0 / 384.0;
    const double twopi = 2.0 * M_PI;
    double fx = (double)(ix < 64 ? ix : ix - 128);
    double fy = (double)(iy < 64 ? iy : iy - 128);
    double fz = (double)(iz < 64 ? iz : iz - 128);
    double kx = __dmul_rn(twopi, __dmul_rn(fx, inv));
    double ky = __dmul_rn(twopi, __dmul_rn(fy, inv));
    double kz = __dmul_rn(twopi, __dmul_rn(fz, inv));
    double sq = __dadd_rn(__dadd_rn(__dmul_rn(kx, kx), __dmul_rn(ky, ky)), __dmul_rn(kz, kz));
    double kmag = sqrt(sq);
    if (!(kmag > 0.0)) return 100;                   // DC -> dropped bin
    double start, step, stop;
    bin_params(&start, &step, &stop);
    double t = (kmag - start) / step;
    int c = (int)floor(t);
    if (c < -1) c = -1;
    if (c > 100) c = 100;
    // emulate np.digitize(kmag, edges) - 1  (right=False)
    while (c < 100 && kmag >= bin_edge(c + 1, start, step, stop)) ++c;
    while (c >= 0 && kmag < bin_edge(c, start, step, stop)) --c;
    if (c < 0) c = 0;
    if (c > 99) c = 99;
    return c;
}

// ---------------- Stockham radix-2 FFT, length 128, one wave (64 lanes) ----------------
// buf: ping-pong pair of 128 complex. Input in buf[0]; result ends in buf[1].
__device__ __forceinline__ void fft128(float2 (*buf)[128], int lane) {
    int cur = 0;
#pragma unroll
    for (int i = 0; i < 7; ++i) {
        const int s = 1 << i;
        const int q = lane & (s - 1);
        const int p = lane >> i;
        float2 a = buf[cur][lane];
        float2 b = buf[cur][lane + 64];
        float ang = -6.28318530717958647692f * ((float)p / (float)(128 >> i));
        float sn, cs;
        __sincosf(ang, &sn, &cs);
        float2 t0 = make_float2(a.x + b.x, a.y + b.y);
        float dx = a.x - b.x, dy = a.y - b.y;
        float2 t1 = make_float2(dx * cs - dy * sn, dx * sn + dy * cs);
        buf[1 - cur][2 * lane - q]     = t0;
        buf[1 - cur][2 * lane - q + s] = t1;
        cur ^= 1;
        __syncthreads();
    }
    // result in buf[1]
}

// ---------------- kernels ----------------
__global__ __launch_bounds__(256) void k_zero(float* sums, int* counts) {
    int t = blockIdx.x * 256 + threadIdx.x;
    if (t < NFIELDS * 101) sums[t] = 0.0f;
    if (t < 101) counts[t] = 0;
}

__global__ __launch_bounds__(256) void k_ids(unsigned char* __restrict__ ids,
                                             int* __restrict__ counts) {
    __shared__ int lcnt[101];
    int tid = threadIdx.x;
    if (tid < 101) lcnt[tid] = 0;
    __syncthreads();
    int idx = blockIdx.x * 256 + tid;
    int iz = idx & 127;
    int iy = (idx >> 7) & 127;
    int ix = idx >> 14;
    int id = compute_bin(ix, iy, iz);
    ids[idx] = (unsigned char)id;
    if (id < 100) atomicAdd(&lcnt[id], 1);
    __syncthreads();
    if (tid < 101 && lcnt[tid]) atomicAdd(&counts[tid], lcnt[tid]);
}

// Pass 0: FFT along z (contiguous). real in -> complex out. 4 lines/block.
__global__ __launch_bounds__(256) void k_fft_z(const float* __restrict__ in,
                                               float2* __restrict__ out) {
    __shared__ float2 buf[4][2][128];
    int w = threadIdx.x >> 6, lane = threadIdx.x & 63;
    size_t li = (size_t)blockIdx.x * 4 + w;          // line index over (x,y)
    const float* src = in + li * 128;
    buf[w][0][lane]      = make_float2(src[lane], 0.0f);
    buf[w][0][lane + 64] = make_float2(src[lane + 64], 0.0f);
    __syncthreads();
    fft128(buf[w], lane);
    float2* dst = out + li * 128;
    dst[lane]      = buf[w][1][lane];
    dst[lane + 64] = buf[w][1][lane + 64];
}

// Pass 1: FFT along y (stride 128), in-place. Block: fixed x, 4 consecutive z.
__global__ __launch_bounds__(256) void k_fft_y(float2* __restrict__ data) {
    __shared__ float2 buf[4][2][128];
    int tid = threadIdx.x;
    int x  = blockIdx.x >> 5;
    int z0 = (blockIdx.x & 31) << 2;
#pragma unroll
    for (int it = 0; it < 2; ++it) {
        int lin = tid + it * 256;
        int y = lin >> 2, dz = lin & 3;
        buf[dz][0][y] = data[(size_t)x * 16384 + (size_t)y * 128 + z0 + dz];
    }
    __syncthreads();
    fft128(buf[tid >> 6], tid & 63);
#pragma unroll
    for (int it = 0; it < 2; ++it) {
        int lin = tid + it * 256;
        int y = lin >> 2, dz = lin & 3;
        data[(size_t)x * 16384 + (size_t)y * 128 + z0 + dz] = buf[dz][1][y];
    }
}

// Pass 2: FFT along x (stride 16384) + power + radial binning. Block: fixed y, 4 z.
__global__ __launch_bounds__(256) void k_fft_x_bin(const float2* __restrict__ data,
                                                   const unsigned char* __restrict__ ids,
                                                   float* __restrict__ sums) {
    __shared__ float2 buf[4][2][128];
    __shared__ float lbins[101];
    int tid = threadIdx.x;
    if (tid < 101) lbins[tid] = 0.0f;
    int y  = blockIdx.x >> 5;
    int z0 = (blockIdx.x & 31) << 2;
#pragma unroll
    for (int it = 0; it < 2; ++it) {
        int lin = tid + it * 256;
        int xx = lin >> 2, dz = lin & 3;
        buf[dz][0][xx] = data[(size_t)xx * 16384 + (size_t)y * 128 + z0 + dz];
    }
    __syncthreads();
    fft128(buf[tid >> 6], tid & 63);
#pragma unroll
    for (int it = 0; it < 2; ++it) {
        int lin = tid + it * 256;
        int xx = lin >> 2, dz = lin & 3;
        float2 c = buf[dz][1][xx];
        float pk = (c.x * c.x + c.y * c.y) * NORMF;
        int id = ids[(size_t)xx * 16384 + (size_t)y * 128 + z0 + dz];
        atomicAdd(&lbins[id], pk);
    }
    __syncthreads();
    if (tid < 101) {
        float v = lbins[tid];
        if (v != 0.0f) atomicAdd(&sums[tid], v);
    }
}

// Finalize: Delta^2, log10 ratio, nanmean -> scalar.
__global__ __launch_bounds__(128) void k_finalize(const float* __restrict__ sums,
                                                  const int* __restrict__ counts,
                                                  float* __restrict__ out) {
    __shared__ double ssum[128];
    __shared__ int scnt[128];
    int k = threadIdx.x;
    double local = 0.0;
    int nloc = 0;
    if (k < KBINS) {
        int c = counts[k];
        if (c > 0) {
            double start, step, stop;
            bin_params(&start, &step, &stop);
            double e0 = bin_edge(k, start, step, stop);
            double e1 = bin_edge(k + 1, start, step, stop);
            float kc  = (float)(0.5 * (e0 + e1));    // matches kcent astype(float32)
            float kc3 = kc * kc * kc;                // kc ** 3 in fp32
            const float two_pi2 = (float)(2.0 * M_PI * M_PI);
            float cf = (float)c;
            for (int b = 0; b < 8; ++b) {
                float pm_p = sums[b * 101 + k] / cf;         // pred
                float pm_t = sums[(8 + b) * 101 + k] / cf;   // target
                float dsq_p = pm_p * kc3 / two_pi2;
                float dsq_t = pm_t * kc3 / two_pi2;
                float d = fabsf(log10f(dsq_t) - log10f(dsq_p));
                local += (double)d;
            }
            nloc = 8;
        }
    }
    ssum[k] = local;
    scnt[k] = nloc;
    __syncthreads();
    for (int off = 64; off > 0; off >>= 1) {
        if (k < off) { ssum[k] += ssum[k + off]; scnt[k] += scnt[k + off]; }
        __syncthreads();
    }
    if (k == 0) out[0] = (float)(ssum[0] / (double)scnt[0]);
}

// ---------------- launch ----------------
extern "C" void kernel_launch(void* const* d_in, const int* in_sizes, int n_in,
                              void* d_out, int out_size, void* d_ws, size_t ws_size,
                              hipStream_t stream) {
    (void)in_sizes; (void)n_in; (void)out_size; (void)ws_size;
    const float* pred   = (const float*)d_in[0];
    const float* target = (const float*)d_in[1];
    float* out = (float*)d_out;
    char* ws = (char*)d_ws;

    float* sums          = (float*)(ws + WS_SUMS_OFF);   // [16][101]
    int* counts          = (int*)(ws + WS_CNT_OFF);      // [101]
    unsigned char* ids   = (unsigned char*)(ws + WS_IDS_OFF);
    float2* cplx         = (float2*)(ws + WS_CPLX_OFF);

    k_zero<<<7, 256, 0, stream>>>(sums, counts);
    k_ids<<<NVOX / 256, 256, 0, stream>>>(ids, counts);

    for (int f = 0; f < NFIELDS; ++f) {
        const float* src = (f < 8) ? (pred + (size_t)f * NVOX)
                                   : (target + (size_t)(f - 8) * NVOX);
        k_fft_z<<<16384 / 4, 256, 0, stream>>>(src, cplx);
        k_fft_y<<<4096, 256, 0, stream>>>(cplx);
        k_fft_x_bin<<<4096, 256, 0, stream>>>(cplx, ids, sums + f * 101);
    }

    k_finalize<<<1, 128, 0, stream>>>(sums, counts, out);
}

// Round 2
// 1085.219 us; speedup vs baseline: 2.1827x; 2.1827x over previous
//
#include <hip/hip_runtime.h>
#include <math.h>

#ifndef M_PI
#define M_PI 3.14159265358979323846
#endif

// ---------------- constants ----------------
#define NSIDE 128
#define NVOX  2097152          // 128^3
#define KBINS 100
#define NFIELDS 16             // 8 pred + 8 target
#define NORMF (27.0f / 2097152.0f)   // LPIX^3 / N^3

// ws layout (bytes)
#define WS_SUMS_OFF   0                       // float[16*101]
#define WS_CNT_OFF    6464                    // int[101]
#define WS_IDS_OFF    8192                    // uint8[NVOX]
#define WS_CPLX_OFF   (8192 + 2097152)        // float2[NVOX]

// ---------------- exact numpy binning replication (fp64) ----------------
__device__ __forceinline__ double bin_edge(int i, double start, double step, double stop) {
    if (i == 100) return stop;                       // linspace sets last edge exactly
    return __dadd_rn(__dmul_rn((double)i, step), start);  // i*step + start, no FMA
}

__device__ __forceinline__ void bin_params(double* start, double* step, double* stop) {
    const double inv   = 1.0 / 384.0;                // 1/(n*d)
    const double twopi = 2.0 * M_PI;
    double k1 = __dmul_rn(twopi, __dmul_rn(1.0, inv));
    *start = sqrt(__dadd_rn(__dadd_rn(0.0, 0.0), __dmul_rn(k1, k1)));
    double k64 = __dmul_rn(twopi, __dmul_rn(-64.0, inv));
    double s64 = __dmul_rn(k64, k64);
    *stop = sqrt(__dadd_rn(__dadd_rn(s64, s64), s64));
    *step = (*stop - *start) / 100.0;
}

__device__ int compute_bin(int ix, int iy, int iz) {
    const double inv   = 1.0 / 384.0;
    const double twopi = 2.0 * M_PI;
    double fx = (double)(ix < 64 ? ix : ix - 128);
    double fy = (double)(iy < 64 ? iy : iy - 128);
    double fz = (double)(iz < 64 ? iz : iz - 128);
    double kx = __dmul_rn(twopi, __dmul_rn(fx, inv));
    double ky = __dmul_rn(twopi, __dmul_rn(fy, inv));
    double kz = __dmul_rn(twopi, __dmul_rn(fz, inv));
    double sq = __dadd_rn(__dadd_rn(__dmul_rn(kx, kx), __dmul_rn(ky, ky)), __dmul_rn(kz, kz));
    double kmag = sqrt(sq);
    if (!(kmag > 0.0)) return 100;                   // DC -> dropped bin
    double start, step, stop;
    bin_params(&start, &step, &stop);
    double t = (kmag - start) / step;
    int c = (int)floor(t);
    if (c < -1) c = -1;
    if (c > 100) c = 100;
    while (c < 100 && kmag >= bin_edge(c + 1, start, step, stop)) ++c;
    while (c >= 0 && kmag < bin_edge(c, start, step, stop)) --c;
    if (c < 0) c = 0;
    if (c > 99) c = 99;
    return c;
}

// ---------------- Stockham radix-2 FFT, length 128, one wave (64 lanes) ----------------
// Wave-private line buffer: buf[2][LW]. Input in buf[0]; result ends in buf[1].
// No __syncthreads needed between stages: only this wave touches this buffer,
// a wave-local s_waitcnt lgkmcnt(0) orders the LDS writes before the reads.
template <int LW>
__device__ __forceinline__ void fft128_wave(float2 (*buf)[LW], int lane) {
    int cur = 0;
#pragma unroll
    for (int i = 0; i < 7; ++i) {
        const int s = 1 << i;
        const int q = lane & (s - 1);
        const int p = lane >> i;
        float2 a = buf[cur][lane];
        float2 b = buf[cur][lane + 64];
        float ang = -6.28318530717958647692f * ((float)p / (float)(128 >> i));
        float sn, cs;
        __sincosf(ang, &sn, &cs);
        float2 t0 = make_float2(a.x + b.x, a.y + b.y);
        float dx = a.x - b.x, dy = a.y - b.y;
        float2 t1 = make_float2(dx * cs - dy * sn, dx * sn + dy * cs);
        buf[1 - cur][2 * lane - q]     = t0;
        buf[1 - cur][2 * lane - q + s] = t1;
        cur ^= 1;
        __asm__ volatile("s_waitcnt lgkmcnt(0)" ::: "memory");
    }
    // result in buf[1]
}

// ---------------- kernels ----------------
__global__ __launch_bounds__(256) void k_zero(float* sums, int* counts) {
    int t = blockIdx.x * 256 + threadIdx.x;
    if (t < NFIELDS * 101) sums[t] = 0.0f;
    if (t < 101) counts[t] = 0;
}

__global__ __launch_bounds__(256) void k_ids(unsigned char* __restrict__ ids,
                                             int* __restrict__ counts) {
    __shared__ int lcnt[101];
    int tid = threadIdx.x;
    if (tid < 101) lcnt[tid] = 0;
    __syncthreads();
    int idx = blockIdx.x * 256 + tid;
    int iz = idx & 127;
    int iy = (idx >> 7) & 127;
    int ix = idx >> 14;
    int id = compute_bin(ix, iy, iz);
    ids[idx] = (unsigned char)id;
    if (id < 100) atomicAdd(&lcnt[id], 1);
    __syncthreads();
    if (tid < 101 && lcnt[tid]) atomicAdd(&counts[tid], lcnt[tid]);
}

// Pass 0: FFT along z (contiguous). real in -> complex out. 4 lines/block,
// each wave owns one line end-to-end -> no block barriers at all.
__global__ __launch_bounds__(256) void k_fft_z(const float* __restrict__ in,
                                               float2* __restrict__ out) {
    __shared__ float2 buf[4][2][128];
    int w = threadIdx.x >> 6, lane = threadIdx.x & 63;
    size_t li = (size_t)blockIdx.x * 4 + w;          // line index over (x,y)
    const float* src = in + li * 128;
    buf[w][0][lane]      = make_float2(src[lane], 0.0f);
    buf[w][0][lane + 64] = make_float2(src[lane + 64], 0.0f);
    __asm__ volatile("s_waitcnt lgkmcnt(0)" ::: "memory");
    fft128_wave<128>(buf[w], lane);
    float2* dst = out + li * 128;
    dst[lane]      = buf[w][1][lane];
    dst[lane + 64] = buf[w][1][lane + 64];
}

// Pass 1: FFT along y (stride 128), in-place. Block: fixed x, 16 consecutive z.
// 1024 threads = 16 waves; wave dz runs line dz. Loads/stores are 128B
// contiguous per (x,y) line (16 z * float2).
__global__ __launch_bounds__(1024) void k_fft_y(float2* __restrict__ data) {
    __shared__ float2 buf[16][2][129];               // pad 129: dz-major lanes 2-way/bank
    int tid = threadIdx.x;
    int x  = blockIdx.x >> 3;
    int z0 = (blockIdx.x & 7) << 4;
#pragma unroll
    for (int it = 0; it < 2; ++it) {
        int lin = tid + it * 1024;
        int y = lin >> 4, dz = lin & 15;
        buf[dz][0][y] = data[(size_t)x * 16384 + (size_t)y * 128 + z0 + dz];
    }
    __syncthreads();
    fft128_wave<129>(buf[tid >> 6], tid & 63);
    __syncthreads();
#pragma unroll
    for (int it = 0; it < 2; ++it) {
        int lin = tid + it * 1024;
        int y = lin >> 4, dz = lin & 15;
        data[(size_t)x * 16384 + (size_t)y * 128 + z0 + dz] = buf[dz][1][y];
    }
}

// Pass 2: FFT along x (stride 16384) + power + radial binning. Block: fixed y,
// 16 consecutive z. ids read via permutation symmetry ids[x][y][z]==ids[y][x][z]
// so the byte reads are contiguous per line too.
__global__ __launch_bounds__(1024) void k_fft_x_bin(const float2* __restrict__ data,
                                                    const unsigned char* __restrict__ ids,
                                                    float* __restrict__ sums) {
    __shared__ float2 buf[16][2][129];
    __shared__ float lbins[101];
    int tid = threadIdx.x;
    if (tid < 101) lbins[tid] = 0.0f;
    int y  = blockIdx.x >> 3;
    int z0 = (blockIdx.x & 7) << 4;
#pragma unroll
    for (int it = 0; it < 2; ++it) {
        int lin = tid + it * 1024;
        int xx = lin >> 4, dz = lin & 15;
        buf[dz][0][xx] = data[(size_t)xx * 16384 + (size_t)y * 128 + z0 + dz];
    }
    __syncthreads();
    fft128_wave<129>(buf[tid >> 6], tid & 63);
    __syncthreads();
#pragma unroll
    for (int it = 0; it < 2; ++it) {
        int lin = tid + it * 1024;
        int xx = lin >> 4, dz = lin & 15;
        float2 c = buf[dz][1][xx];
        float pk = (c.x * c.x + c.y * c.y) * NORMF;
        int id = ids[(size_t)y * 16384 + (size_t)xx * 128 + z0 + dz];  // symmetric
        atomicAdd(&lbins[id], pk);
    }
    __syncthreads();
    if (tid < 101) {
        float v = lbins[tid];
        if (v != 0.0f) atomicAdd(&sums[tid], v);
    }
}

// Finalize: Delta^2, log10 ratio, nanmean -> scalar.
__global__ __launch_bounds__(128) void k_finalize(const float* __restrict__ sums,
                                                  const int* __restrict__ counts,
                                                  float* __restrict__ out) {
    __shared__ double ssum[128];
    __shared__ int scnt[128];
    int k = threadIdx.x;
    double local = 0.0;
    int nloc = 0;
    if (k < KBINS) {
        int c = counts[k];
        if (c > 0) {
            double start, step, stop;
            bin_params(&start, &step, &stop);
            double e0 = bin_edge(k, start, step, stop);
            double e1 = bin_edge(k + 1, start, step, stop);
            float kc  = (float)(0.5 * (e0 + e1));    // matches kcent astype(float32)
            float kc3 = kc * kc * kc;                // kc ** 3 in fp32
            const float two_pi2 = (float)(2.0 * M_PI * M_PI);
            float cf = (float)c;
            for (int b = 0; b < 8; ++b) {
                float pm_p = sums[b * 101 + k] / cf;         // pred
                float pm_t = sums[(8 + b) * 101 + k] / cf;   // target
                float dsq_p = pm_p * kc3 / two_pi2;
                float dsq_t = pm_t * kc3 / two_pi2;
                float d = fabsf(log10f(dsq_t) - log10f(dsq_p));
                local += (double)d;
            }
            nloc = 8;
        }
    }
    ssum[k] = local;
    scnt[k] = nloc;
    __syncthreads();
    for (int off = 64; off > 0; off >>= 1) {
        if (k < off) { ssum[k] += ssum[k + off]; scnt[k] += scnt[k + off]; }
        __syncthreads();
    }
    if (k == 0) out[0] = (float)(ssum[0] / (double)scnt[0]);
}

// ---------------- launch ----------------
extern "C" void kernel_launch(void* const* d_in, const int* in_sizes, int n_in,
                              void* d_out, int out_size, void* d_ws, size_t ws_size,
                              hipStream_t stream) {
    (void)in_sizes; (void)n_in; (void)out_size; (void)ws_size;
    const float* pred   = (const float*)d_in[0];
    const float* target = (const float*)d_in[1];
    float* out = (float*)d_out;
    char* ws = (char*)d_ws;

    float* sums          = (float*)(ws + WS_SUMS_OFF);   // [16][101]
    int* counts          = (int*)(ws + WS_CNT_OFF);      // [101]
    unsigned char* ids   = (unsigned char*)(ws + WS_IDS_OFF);
    float2* cplx         = (float2*)(ws + WS_CPLX_OFF);

    k_zero<<<7, 256, 0, stream>>>(sums, counts);
    k_ids<<<NVOX / 256, 256, 0, stream>>>(ids, counts);

    for (int f = 0; f < NFIELDS; ++f) {
        const float* src = (f < 8) ? (pred + (size_t)f * NVOX)
                                   : (target + (size_t)(f - 8) * NVOX);
        k_fft_z<<<16384 / 4, 256, 0, stream>>>(src, cplx);
        k_fft_y<<<1024, 1024, 0, stream>>>(cplx);
        k_fft_x_bin<<<1024, 1024, 0, stream>>>(cplx, ids, sums + f * 101);
    }

    k_finalize<<<1, 128, 0, stream>>>(sums, counts, out);
}

// Round 3
// 813.489 us; speedup vs baseline: 2.9118x; 1.3340x over previous
//
#include <hip/hip_runtime.h>
#include <math.h>

#ifndef M_PI
#define M_PI 3.14159265358979323846
#endif

// ---------------- constants ----------------
#define NSIDE 128
#define NVOX  2097152          // 128^3
#define KBINS 100
#define NFIELDS 16             // 8 pred + 8 target
#define NORMF (27.0f / 2097152.0f)   // LPIX^3 / N^3
#define KZP   80               // padded kz extent (kz 0..64 valid, 65..79 zero)

// ws layout (bytes)
#define WS_SUMS_OFF   0                       // float[16*101]
#define WS_CNT_OFF    6464                    // int[101]
#define WS_OCT_OFF    8192                    // uint8[65*65*65] = 274625
#define WS_CPLX_OFF   294912                  // float2[128*128*KZP] = 10.5 MB

// ---------------- exact numpy binning replication (fp64) ----------------
__device__ __forceinline__ double bin_edge(int i, double start, double step, double stop) {
    if (i == 100) return stop;                       // linspace sets last edge exactly
    return __dadd_rn(__dmul_rn((double)i, step), start);  // i*step + start, no FMA
}

__device__ __forceinline__ void bin_params(double* start, double* step, double* stop) {
    const double inv   = 1.0 / 384.0;                // 1/(n*d)
    const double twopi = 2.0 * M_PI;
    double k1 = __dmul_rn(twopi, __dmul_rn(1.0, inv));
    *start = sqrt(__dadd_rn(__dadd_rn(0.0, 0.0), __dmul_rn(k1, k1)));
    double k64 = __dmul_rn(twopi, __dmul_rn(-64.0, inv));
    double s64 = __dmul_rn(k64, k64);
    *stop = sqrt(__dadd_rn(__dadd_rn(s64, s64), s64));
    *step = (*stop - *start) / 100.0;
}

// Exact numpy digitize path. Axis roles preserved: a=|fx|, b=|fy|, c=|fz|.
// Bit-exact for all 128^3 voxels because fp64 negation is exact and the
// (kx^2+ky^2)+kz^2 summation order is preserved.
__device__ int compute_bin(int ix, int iy, int iz) {
    const double inv   = 1.0 / 384.0;
    const double twopi = 2.0 * M_PI;
    double fx = (double)(ix < 64 ? ix : ix - 128);
    double fy = (double)(iy < 64 ? iy : iy - 128);
    double fz = (double)(iz < 64 ? iz : iz - 128);
    double kx = __dmul_rn(twopi, __dmul_rn(fx, inv));
    double ky = __dmul_rn(twopi, __dmul_rn(fy, inv));
    double kz = __dmul_rn(twopi, __dmul_rn(fz, inv));
    double sq = __dadd_rn(__dadd_rn(__dmul_rn(kx, kx), __dmul_rn(ky, ky)), __dmul_rn(kz, kz));
    double kmag = sqrt(sq);
    if (!(kmag > 0.0)) return 100;                   // DC -> dropped bin
    double start, step, stop;
    bin_params(&start, &step, &stop);
    double t = (kmag - start) / step;
    int c = (int)floor(t);
    if (c < -1) c = -1;
    if (c > 100) c = 100;
    while (c < 100 && kmag >= bin_edge(c + 1, start, step, stop)) ++c;
    while (c >= 0 && kmag < bin_edge(c, start, step, stop)) --c;
    if (c < 0) c = 0;
    if (c > 99) c = 99;
    return c;
}

// ---------------- Stockham radix-2 FFT, length 128, one wave (64 lanes) ----------------
// Wave-private line buffer; inter-stage ordering via wave-local lgkmcnt(0).
// Twiddles: angle is a dyadic rational in revolutions -> v_sin/v_cos directly.
template <int LW>
__device__ __forceinline__ void fft128_wave(float2 (*buf)[LW], int lane) {
    int cur = 0;
#pragma unroll
    for (int i = 0; i < 7; ++i) {
        const int s = 1 << i;
        const int q = lane & (s - 1);
        const int p = lane >> i;
        float2 a = buf[cur][lane];
        float2 b = buf[cur][lane + 64];
        float r = -(float)p * (1.0f / (float)(128 >> i));   // revolutions, exact
        float sn = __builtin_amdgcn_sinf(r);                // sin(2*pi*r)
        float cs = __builtin_amdgcn_cosf(r);
        float2 t0 = make_float2(a.x + b.x, a.y + b.y);
        float dx = a.x - b.x, dy = a.y - b.y;
        float2 t1 = make_float2(dx * cs - dy * sn, dx * sn + dy * cs);
        buf[1 - cur][2 * lane - q]     = t0;
        buf[1 - cur][2 * lane - q + s] = t1;
        cur ^= 1;
        __asm__ volatile("s_waitcnt lgkmcnt(0)" ::: "memory");
    }
    // result in buf[1]
}

// ---------------- kernels ----------------
__global__ __launch_bounds__(256) void k_zero(float* sums, int* counts) {
    int t = blockIdx.x * 256 + threadIdx.x;
    if (t < NFIELDS * 101) sums[t] = 0.0f;
    if (t < 101) counts[t] = 0;
}

// Octant bin table + exact mode counts. 65^3 = 274625 entries.
// weight(axis val v) = (v==0||v==64) ? 1 : 2  (number of ix mapping to |fx|=v)
__global__ __launch_bounds__(256) void k_oct(unsigned char* __restrict__ oct,
                                             int* __restrict__ counts) {
    __shared__ int lcnt[4][104];
    int tid = threadIdx.x;
#pragma unroll
    for (int j = tid; j < 4 * 104; j += 256) ((int*)lcnt)[j] = 0;
    __syncthreads();
    int idx = blockIdx.x * 256 + tid;
    if (idx < 65 * 65 * 65) {
        int c = idx % 65;
        int r = idx / 65;
        int b = r % 65;
        int a = r / 65;
        int id = compute_bin(a, b, c);
        oct[idx] = (unsigned char)id;
        if (id < 100) {
            int w = ((a == 0 || a == 64) ? 1 : 2) *
                    ((b == 0 || b == 64) ? 1 : 2) *
                    ((c == 0 || c == 64) ? 1 : 2);
            atomicAdd(&lcnt[tid & 3][id], w);
        }
    }
    __syncthreads();
    if (tid < 101) {
        int tot = lcnt[0][tid] + lcnt[1][tid] + lcnt[2][tid] + lcnt[3][tid];
        if (tot) atomicAdd(&counts[tid], tot);
    }
}

// Pass 0: FFT along z (contiguous). real in -> complex out, keep kz 0..64 only
// (Hermitian symmetry of real input), pad kz 65..79 with zeros.
__global__ __launch_bounds__(256) void k_fft_z(const float* __restrict__ in,
                                               float2* __restrict__ out) {
    __shared__ float2 buf[4][2][128];
    int w = threadIdx.x >> 6, lane = threadIdx.x & 63;
    size_t li = (size_t)blockIdx.x * 4 + w;          // line index over (x,y)
    const float* src = in + li * 128;
    buf[w][0][lane]      = make_float2(src[lane], 0.0f);
    buf[w][0][lane + 64] = make_float2(src[lane + 64], 0.0f);
    __asm__ volatile("s_waitcnt lgkmcnt(0)" ::: "memory");
    fft128_wave<128>(buf[w], lane);
    float2* dst = out + li * KZP;
    dst[lane] = buf[w][1][lane];                     // kz 0..63
    if (lane < 16)                                   // kz 64 + zero pad 65..79
        dst[64 + lane] = (lane == 0) ? buf[w][1][64] : make_float2(0.0f, 0.0f);
}

// Pass 1: FFT along y (stride KZP), in-place. Block: fixed x, 16 consecutive kz.
// Only 5 kz-tiles (kz 0..79) instead of 8 -> 0.625x work.
__global__ __launch_bounds__(1024) void k_fft_y(float2* __restrict__ data) {
    __shared__ float2 buf[16][2][129];
    int tid = threadIdx.x;
    int x  = blockIdx.x / 5;
    int z0 = (blockIdx.x % 5) << 4;
#pragma unroll
    for (int it = 0; it < 2; ++it) {
        int lin = tid + it * 1024;
        int y = lin >> 4, dz = lin & 15;
        buf[dz][0][y] = data[(size_t)x * (128 * KZP) + (size_t)y * KZP + z0 + dz];
    }
    __syncthreads();
    fft128_wave<129>(buf[tid >> 6], tid & 63);
    __syncthreads();
#pragma unroll
    for (int it = 0; it < 2; ++it) {
        int lin = tid + it * 1024;
        int y = lin >> 4, dz = lin & 15;
        data[(size_t)x * (128 * KZP) + (size_t)y * KZP + z0 + dz] = buf[dz][1][y];
    }
}

// Pass 2: FFT along x + power + radial binning. Block: fixed y, 16 consecutive kz.
// kz in [1,63] weighted 2x (conjugate plane), kz==0/64 weighted 1x, kz>64 skipped.
// Bin id fetched inline from the 262KB octant table (L2-resident).
__global__ __launch_bounds__(1024) void k_fft_x_bin(const float2* __restrict__ data,
                                                    const unsigned char* __restrict__ oct,
                                                    float* __restrict__ sums) {
    __shared__ float2 buf[16][2][129];
    __shared__ float lbins[4][104];
    int tid = threadIdx.x;
#pragma unroll
    for (int j = tid; j < 4 * 104; j += 1024) ((float*)lbins)[j] = 0.0f;
    int y  = blockIdx.x / 5;
    int z0 = (blockIdx.x % 5) << 4;
#pragma unroll
    for (int it = 0; it < 2; ++it) {
        int lin = tid + it * 1024;
        int xx = lin >> 4, dz = lin & 15;
        buf[dz][0][xx] = data[(size_t)xx * (128 * KZP) + (size_t)y * KZP + z0 + dz];
    }
    __syncthreads();
    fft128_wave<129>(buf[tid >> 6], tid & 63);
    __syncthreads();
    int myy = (y <= 64) ? y : 128 - y;
#pragma unroll
    for (int it = 0; it < 2; ++it) {
        int lin = tid + it * 1024;
        int xx = lin >> 4, dz = lin & 15;
        int kz = z0 + dz;
        if (kz <= 64) {
            float2 c = buf[dz][1][xx];
            float wz = (kz == 0 || kz == 64) ? 1.0f : 2.0f;
            float pk = (c.x * c.x + c.y * c.y) * (NORMF) * wz;
            int mxx = (xx <= 64) ? xx : 128 - xx;
            int id = oct[mxx * 4225 + myy * 65 + kz];
            atomicAdd(&lbins[tid & 3][id], pk);
        }
    }
    __syncthreads();
    if (tid < 101) {
        float v = lbins[0][tid] + lbins[1][tid] + lbins[2][tid] + lbins[3][tid];
        if (v != 0.0f) atomicAdd(&sums[tid], v);
    }
}

// Finalize: Delta^2, log10 ratio, nanmean -> scalar.
__global__ __launch_bounds__(128) void k_finalize(const float* __restrict__ sums,
                                                  const int* __restrict__ counts,
                                                  float* __restrict__ out) {
    __shared__ double ssum[128];
    __shared__ int scnt[128];
    int k = threadIdx.x;
    double local = 0.0;
    int nloc = 0;
    if (k < KBINS) {
        int c = counts[k];
        if (c > 0) {
            double start, step, stop;
            bin_params(&start, &step, &stop);
            double e0 = bin_edge(k, start, step, stop);
            double e1 = bin_edge(k + 1, start, step, stop);
            float kc  = (float)(0.5 * (e0 + e1));    // matches kcent astype(float32)
            float kc3 = kc * kc * kc;                // kc ** 3 in fp32
            const float two_pi2 = (float)(2.0 * M_PI * M_PI);
            float cf = (float)c;
            for (int b = 0; b < 8; ++b) {
                float pm_p = sums[b * 101 + k] / cf;         // pred
                float pm_t = sums[(8 + b) * 101 + k] / cf;   // target
                float dsq_p = pm_p * kc3 / two_pi2;
                float dsq_t = pm_t * kc3 / two_pi2;
                float d = fabsf(log10f(dsq_t) - log10f(dsq_p));
                local += (double)d;
            }
            nloc = 8;
        }
    }
    ssum[k] = local;
    scnt[k] = nloc;
    __syncthreads();
    for (int off = 64; off > 0; off >>= 1) {
        if (k < off) { ssum[k] += ssum[k + off]; scnt[k] += scnt[k + off]; }
        __syncthreads();
    }
    if (k == 0) out[0] = (float)(ssum[0] / (double)scnt[0]);
}

// ---------------- launch ----------------
extern "C" void kernel_launch(void* const* d_in, const int* in_sizes, int n_in,
                              void* d_out, int out_size, void* d_ws, size_t ws_size,
                              hipStream_t stream) {
    (void)in_sizes; (void)n_in; (void)out_size; (void)ws_size;
    const float* pred   = (const float*)d_in[0];
    const float* target = (const float*)d_in[1];
    float* out = (float*)d_out;
    char* ws = (char*)d_ws;

    float* sums        = (float*)(ws + WS_SUMS_OFF);   // [16][101]
    int* counts        = (int*)(ws + WS_CNT_OFF);      // [101]
    unsigned char* oct = (unsigned char*)(ws + WS_OCT_OFF);
    float2* cplx       = (float2*)(ws + WS_CPLX_OFF);

    k_zero<<<7, 256, 0, stream>>>(sums, counts);
    k_oct<<<(65 * 65 * 65 + 255) / 256, 256, 0, stream>>>(oct, counts);

    for (int f = 0; f < NFIELDS; ++f) {
        const float* src = (f < 8) ? (pred + (size_t)f * NVOX)
                                   : (target + (size_t)(f - 8) * NVOX);
        k_fft_z<<<16384 / 4, 256, 0, stream>>>(src, cplx);
        k_fft_y<<<128 * 5, 1024, 0, stream>>>(cplx);
        k_fft_x_bin<<<128 * 5, 1024, 0, stream>>>(cplx, oct, sums + f * 101);
    }

    k_finalize<<<1, 128, 0, stream>>>(sums, counts, out);
}

// Round 4
// 427.650 us; speedup vs baseline: 5.5388x; 1.9022x over previous
//
#include <hip/hip_runtime.h>
#include <math.h>

#ifndef M_PI
#define M_PI 3.14159265358979323846
#endif

// ---------------- constants ----------------
#define NSIDE 128
#define NVOX  2097152          // 128^3
#define KBINS 100
#define NFIELDS 16             // 8 pred + 8 target
#define NORMF (27.0f / 2097152.0f)   // LPIX^3 / N^3
#define KZP   80               // padded kz extent (kz 0..64 valid, 65..79 zero)
#define FSTRIDE ((size_t)128 * 128 * KZP)   // complex elems per field buffer

// ws layout (bytes)
#define WS_SUMS_OFF   0                       // float[16*101]
#define WS_CNT_OFF    6464                    // int[101]
#define WS_OCT_OFF    8192                    // uint8[65*65*65] = 274625
#define WS_CPLX_OFF   294912                  // float2[16 * FSTRIDE] = 167.8 MB

// ---------------- exact numpy binning replication (fp64) ----------------
__device__ __forceinline__ double bin_edge(int i, double start, double step, double stop) {
    if (i == 100) return stop;                       // linspace sets last edge exactly
    return __dadd_rn(__dmul_rn((double)i, step), start);  // i*step + start, no FMA
}

__device__ __forceinline__ void bin_params(double* start, double* step, double* stop) {
    const double inv   = 1.0 / 384.0;                // 1/(n*d)
    const double twopi = 2.0 * M_PI;
    double k1 = __dmul_rn(twopi, __dmul_rn(1.0, inv));
    *start = sqrt(__dadd_rn(__dadd_rn(0.0, 0.0), __dmul_rn(k1, k1)));
    double k64 = __dmul_rn(twopi, __dmul_rn(-64.0, inv));
    double s64 = __dmul_rn(k64, k64);
    *stop = sqrt(__dadd_rn(__dadd_rn(s64, s64), s64));
    *step = (*stop - *start) / 100.0;
}

// Exact numpy digitize path. Axis roles preserved: a=|fx|, b=|fy|, c=|fz|.
__device__ int compute_bin(int ix, int iy, int iz) {
    const double inv   = 1.0 / 384.0;
    const double twopi = 2.0 * M_PI;
    double fx = (double)(ix < 64 ? ix : ix - 128);
    double fy = (double)(iy < 64 ? iy : iy - 128);
    double fz = (double)(iz < 64 ? iz : iz - 128);
    double kx = __dmul_rn(twopi, __dmul_rn(fx, inv));
    double ky = __dmul_rn(twopi, __dmul_rn(fy, inv));
    double kz = __dmul_rn(twopi, __dmul_rn(fz, inv));
    double sq = __dadd_rn(__dadd_rn(__dmul_rn(kx, kx), __dmul_rn(ky, ky)), __dmul_rn(kz, kz));
    double kmag = sqrt(sq);
    if (!(kmag > 0.0)) return 100;                   // DC -> dropped bin
    double start, step, stop;
    bin_params(&start, &step, &stop);
    double t = (kmag - start) / step;
    int c = (int)floor(t);
    if (c < -1) c = -1;
    if (c > 100) c = 100;
    while (c < 100 && kmag >= bin_edge(c + 1, start, step, stop)) ++c;
    while (c >= 0 && kmag < bin_edge(c, start, step, stop)) --c;
    if (c < 0) c = 0;
    if (c > 99) c = 99;
    return c;
}

// ---------------- Stockham radix-2 FFT, length 128, one wave (64 lanes) ----------------
template <int LW>
__device__ __forceinline__ void fft128_wave(float2 (*buf)[LW], int lane) {
    int cur = 0;
#pragma unroll
    for (int i = 0; i < 7; ++i) {
        const int s = 1 << i;
        const int q = lane & (s - 1);
        const int p = lane >> i;
        float2 a = buf[cur][lane];
        float2 b = buf[cur][lane + 64];
        float r = -(float)p * (1.0f / (float)(128 >> i));   // revolutions, exact
        float sn = __builtin_amdgcn_sinf(r);                // sin(2*pi*r)
        float cs = __builtin_amdgcn_cosf(r);
        float2 t0 = make_float2(a.x + b.x, a.y + b.y);
        float dx = a.x - b.x, dy = a.y - b.y;
        float2 t1 = make_float2(dx * cs - dy * sn, dx * sn + dy * cs);
        buf[1 - cur][2 * lane - q]     = t0;
        buf[1 - cur][2 * lane - q + s] = t1;
        cur ^= 1;
        __asm__ volatile("s_waitcnt lgkmcnt(0)" ::: "memory");
    }
    // result in buf[1]
}

// ---------------- kernels ----------------
__global__ __launch_bounds__(256) void k_zero(float* sums, int* counts) {
    int t = blockIdx.x * 256 + threadIdx.x;
    if (t < NFIELDS * 101) sums[t] = 0.0f;
    if (t < 101) counts[t] = 0;
}

// Octant bin table + exact mode counts. 65^3 = 274625 entries.
__global__ __launch_bounds__(256) void k_oct(unsigned char* __restrict__ oct,
                                             int* __restrict__ counts) {
    __shared__ int lcnt[4][104];
    int tid = threadIdx.x;
#pragma unroll
    for (int j = tid; j < 4 * 104; j += 256) ((int*)lcnt)[j] = 0;
    __syncthreads();
    int idx = blockIdx.x * 256 + tid;
    if (idx < 65 * 65 * 65) {
        int c = idx % 65;
        int r = idx / 65;
        int b = r % 65;
        int a = r / 65;
        int id = compute_bin(a, b, c);
        oct[idx] = (unsigned char)id;
        if (id < 100) {
            int w = ((a == 0 || a == 64) ? 1 : 2) *
                    ((b == 0 || b == 64) ? 1 : 2) *
                    ((c == 0 || c == 64) ? 1 : 2);
            atomicAdd(&lcnt[tid & 3][id], w);
        }
    }
    __syncthreads();
    if (tid < 101) {
        int tot = lcnt[0][tid] + lcnt[1][tid] + lcnt[2][tid] + lcnt[3][tid];
        if (tot) atomicAdd(&counts[tid], tot);
    }
}

// Pass 0 (all fields): FFT along z. real in -> complex out, keep kz 0..64,
// pad 65..79 with zeros. blockIdx.y = field.
__global__ __launch_bounds__(256) void k_fft_z(const float* __restrict__ pred,
                                               const float* __restrict__ target,
                                               float2* __restrict__ cplx) {
    __shared__ float2 buf[4][2][128];
    int f = blockIdx.y;
    const float* in = (f < 8) ? (pred + (size_t)f * NVOX)
                              : (target + (size_t)(f - 8) * NVOX);
    float2* out = cplx + (size_t)f * FSTRIDE;
    int w = threadIdx.x >> 6, lane = threadIdx.x & 63;
    size_t li = (size_t)blockIdx.x * 4 + w;          // line index over (x,y)
    const float* src = in + li * 128;
    buf[w][0][lane]      = make_float2(src[lane], 0.0f);
    buf[w][0][lane + 64] = make_float2(src[lane + 64], 0.0f);
    __asm__ volatile("s_waitcnt lgkmcnt(0)" ::: "memory");
    fft128_wave<128>(buf[w], lane);
    float2* dst = out + li * KZP;
    dst[lane] = buf[w][1][lane];                     // kz 0..63
    if (lane < 16)                                   // kz 64 + zero pad 65..79
        dst[64 + lane] = (lane == 0) ? buf[w][1][64] : make_float2(0.0f, 0.0f);
}

// Pass 1 (all fields): FFT along y (stride KZP), in-place. blockIdx.y = field.
// Block: fixed x, 16 consecutive kz; 5 kz-tiles per x.
__global__ __launch_bounds__(1024) void k_fft_y(float2* __restrict__ cplx) {
    __shared__ float2 buf[16][2][129];
    float2* data = cplx + (size_t)blockIdx.y * FSTRIDE;
    int tid = threadIdx.x;
    int x  = blockIdx.x / 5;
    int z0 = (blockIdx.x % 5) << 4;
#pragma unroll
    for (int it = 0; it < 2; ++it) {
        int lin = tid + it * 1024;
        int y = lin >> 4, dz = lin & 15;
        buf[dz][0][y] = data[(size_t)x * (128 * KZP) + (size_t)y * KZP + z0 + dz];
    }
    __syncthreads();
    fft128_wave<129>(buf[tid >> 6], tid & 63);
    __syncthreads();
#pragma unroll
    for (int it = 0; it < 2; ++it) {
        int lin = tid + it * 1024;
        int y = lin >> 4, dz = lin & 15;
        data[(size_t)x * (128 * KZP) + (size_t)y * KZP + z0 + dz] = buf[dz][1][y];
    }
}

// Pass 2 (all fields): FFT along x + power + radial binning. blockIdx.y = field.
// kz in [1,63] weighted 2x (Hermitian conjugate plane), kz==0/64 weighted 1x.
__global__ __launch_bounds__(1024) void k_fft_x_bin(const float2* __restrict__ cplx,
                                                    const unsigned char* __restrict__ oct,
                                                    float* __restrict__ sums) {
    __shared__ float2 buf[16][2][129];
    __shared__ float lbins[4][104];
    int f = blockIdx.y;
    const float2* data = cplx + (size_t)f * FSTRIDE;
    int tid = threadIdx.x;
#pragma unroll
    for (int j = tid; j < 4 * 104; j += 1024) ((float*)lbins)[j] = 0.0f;
    int y  = blockIdx.x / 5;
    int z0 = (blockIdx.x % 5) << 4;
#pragma unroll
    for (int it = 0; it < 2; ++it) {
        int lin = tid + it * 1024;
        int xx = lin >> 4, dz = lin & 15;
        buf[dz][0][xx] = data[(size_t)xx * (128 * KZP) + (size_t)y * KZP + z0 + dz];
    }
    __syncthreads();
    fft128_wave<129>(buf[tid >> 6], tid & 63);
    __syncthreads();
    int myy = (y <= 64) ? y : 128 - y;
#pragma unroll
    for (int it = 0; it < 2; ++it) {
        int lin = tid + it * 1024;
        int xx = lin >> 4, dz = lin & 15;
        int kz = z0 + dz;
        if (kz <= 64) {
            float2 c = buf[dz][1][xx];
            float wz = (kz == 0 || kz == 64) ? 1.0f : 2.0f;
            float pk = (c.x * c.x + c.y * c.y) * (NORMF) * wz;
            int mxx = (xx <= 64) ? xx : 128 - xx;
            int id = oct[mxx * 4225 + myy * 65 + kz];
            atomicAdd(&lbins[tid & 3][id], pk);
        }
    }
    __syncthreads();
    if (tid < 101) {
        float v = lbins[0][tid] + lbins[1][tid] + lbins[2][tid] + lbins[3][tid];
        if (v != 0.0f) atomicAdd(&sums[f * 101 + tid], v);
    }
}

// Finalize: Delta^2, log10 ratio, nanmean -> scalar.
__global__ __launch_bounds__(128) void k_finalize(const float* __restrict__ sums,
                                                  const int* __restrict__ counts,
                                                  float* __restrict__ out) {
    __shared__ double ssum[128];
    __shared__ int scnt[128];
    int k = threadIdx.x;
    double local = 0.0;
    int nloc = 0;
    if (k < KBINS) {
        int c = counts[k];
        if (c > 0) {
            double start, step, stop;
            bin_params(&start, &step, &stop);
            double e0 = bin_edge(k, start, step, stop);
            double e1 = bin_edge(k + 1, start, step, stop);
            float kc  = (float)(0.5 * (e0 + e1));    // matches kcent astype(float32)
            float kc3 = kc * kc * kc;                // kc ** 3 in fp32
            const float two_pi2 = (float)(2.0 * M_PI * M_PI);
            float cf = (float)c;
            for (int b = 0; b < 8; ++b) {
                float pm_p = sums[b * 101 + k] / cf;         // pred
                float pm_t = sums[(8 + b) * 101 + k] / cf;   // target
                float dsq_p = pm_p * kc3 / two_pi2;
                float dsq_t = pm_t * kc3 / two_pi2;
                float d = fabsf(log10f(dsq_t) - log10f(dsq_p));
                local += (double)d;
            }
            nloc = 8;
        }
    }
    ssum[k] = local;
    scnt[k] = nloc;
    __syncthreads();
    for (int off = 64; off > 0; off >>= 1) {
        if (k < off) { ssum[k] += ssum[k + off]; scnt[k] += scnt[k + off]; }
        __syncthreads();
    }
    if (k == 0) out[0] = (float)(ssum[0] / (double)scnt[0]);
}

// ---------------- launch ----------------
extern "C" void kernel_launch(void* const* d_in, const int* in_sizes, int n_in,
                              void* d_out, int out_size, void* d_ws, size_t ws_size,
                              hipStream_t stream) {
    (void)in_sizes; (void)n_in; (void)out_size; (void)ws_size;
    const float* pred   = (const float*)d_in[0];
    const float* target = (const float*)d_in[1];
    float* out = (float*)d_out;
    char* ws = (char*)d_ws;

    float* sums        = (float*)(ws + WS_SUMS_OFF);   // [16][101]
    int* counts        = (int*)(ws + WS_CNT_OFF);      // [101]
    unsigned char* oct = (unsigned char*)(ws + WS_OCT_OFF);
    float2* cplx       = (float2*)(ws + WS_CPLX_OFF);  // [16][FSTRIDE]

    k_zero<<<7, 256, 0, stream>>>(sums, counts);
    k_oct<<<(65 * 65 * 65 + 255) / 256, 256, 0, stream>>>(oct, counts);

    k_fft_z<<<dim3(16384 / 4, NFIELDS), 256, 0, stream>>>(pred, target, cplx);
    k_fft_y<<<dim3(128 * 5, NFIELDS), 1024, 0, stream>>>(cplx);
    k_fft_x_bin<<<dim3(128 * 5, NFIELDS), 1024, 0, stream>>>(cplx, oct, sums);

    k_finalize<<<1, 128, 0, stream>>>(sums, counts, out);
}